// Round 5
// baseline (201.503 us; speedup 1.0000x reference)
//
#include <hip/hip_runtime.h>
#include <hip/hip_bf16.h>

// KAN layer: out[b,o] = sum_{i,k} exp(-(x[b,i]-c[k])^2/(2 w[k]^2)) * W[o,i,k] + bias[o]
// == GEMM: A = feat[B][I*K] (bf16), Bmat = W[O][I*K] (bf16), C = A * Bmat^T.
// M=4096, N=1024, Kd=16384.
// R5: identical 8-phase counted-vmcnt schedule + fragment-reuse as R4
// (verified), but MFMA shape 16x16x32 -> 32x32x16 (2495 vs 2176 TF ceiling,
// m119; half the MFMA instruction issues per phase). ds_read count unchanged
// (24 b128/tile/wave), balanced bank pattern.

#define B_DIM 4096
#define I_DIM 1024
#define O_DIM 1024
#define NK 16
#define KD (I_DIM * NK)  // 16384

typedef unsigned short u16;
typedef __attribute__((ext_vector_type(8))) __bf16 bf16x8;
typedef __attribute__((ext_vector_type(4))) float f32x4;
typedef __attribute__((ext_vector_type(16))) float f32x16;
typedef __attribute__((ext_vector_type(8))) unsigned short u16x8;

typedef const __attribute__((address_space(1))) unsigned short gu16;
typedef __attribute__((address_space(3))) unsigned short lu16;

static __device__ __forceinline__ u16 f2bf(float f) {
  unsigned u = __float_as_uint(f);
  u += 0x7FFFu + ((u >> 16) & 1u);
  return (u16)(u >> 16);
}

// ---------------------------------------------------------------------------
// Phase 1: RBF features, bf16. One thread per (b,i): 16 exps, two 16B stores.
// ---------------------------------------------------------------------------
__global__ void __launch_bounds__(256) rbf_feat(const float* __restrict__ x,
                                                u16* __restrict__ feat,
                                                const float* __restrict__ centers,
                                                const float* __restrict__ widths) {
  const int idx = blockIdx.x * 256 + threadIdx.x;
  const float xv = x[idx];
  u16x8 lo, hi;
#pragma unroll
  for (int k = 0; k < 16; ++k) {
    const float c = centers[k];
    const float w = widths[k];
    const float s = -0.5f * __builtin_amdgcn_rcpf(w * w);
    const float d = xv - c;
    const u16 h = f2bf(__expf(d * d * s));
    if (k < 8) lo[k] = h; else hi[k - 8] = h;
  }
  u16x8* dst = (u16x8*)(feat + (size_t)idx * 16);
  dst[0] = lo;
  dst[1] = hi;
}

// ---------------------------------------------------------------------------
// Phase 1b: weights f32 -> bf16, 8 elements/thread.
// ---------------------------------------------------------------------------
__global__ void __launch_bounds__(256) cvt_w(const float4* __restrict__ w,
                                             u16x8* __restrict__ wb) {
  const size_t i = (size_t)blockIdx.x * 256 + threadIdx.x;
  const float4 a = w[2 * i];
  const float4 b = w[2 * i + 1];
  u16x8 o;
  o[0] = f2bf(a.x); o[1] = f2bf(a.y); o[2] = f2bf(a.z); o[3] = f2bf(a.w);
  o[4] = f2bf(b.x); o[5] = f2bf(b.y); o[6] = f2bf(b.z); o[7] = f2bf(b.w);
  wb[i] = o;
}

// ---------------------------------------------------------------------------
// Stage one 128x64 bf16 half-tile (16 KiB = 1024 x 16B chunks, 512 thr x 2).
// Linear LDS dest + inverse-swizzled global source (rule #21).
// ---------------------------------------------------------------------------
static __device__ __forceinline__ void stage_half(const u16* __restrict__ g,
                                                  u16* __restrict__ lds, int t) {
#pragma unroll
  for (int j = 0; j < 2; ++j) {
    const int chunk = j * 512 + t;
    const int row = chunk >> 3, slot = chunk & 7;
    const int c = slot ^ (row & 7);
    __builtin_amdgcn_global_load_lds((gu16*)(g + (size_t)row * KD + c * 8),
                                     (lu16*)(lds + chunk * 8), 16, 0, 0);
  }
}

// ---------------------------------------------------------------------------
// Main GEMM: 256x256 tile, BK=64, 8 waves (2M x 4N), split-K=4 (blockIdx.z).
// 32x32x16 MFMA. Per wave: 128x64 output = 4 m-frags x 2 n-frags of 32x32.
// Quadrant walk (0,0),(0,1),(1,1),(1,0) with fragment reuse:
// p0 reads A0(8)+B0(4), p1 reads B1(4), p2 reads A1(8), p3 reads nothing.
// 8 MFMA per phase (2 m-frags x 1 n-frag x 4 k-steps of K=16).
// Stage stream: p0:A1(T+1) p1:B1(T+1) p2:B0(T+2) p3:A0(T+2);
// vmcnt(4) only at tile end. Sync structure identical to R3/R4 (verified).
// A-frag: row=l&31, k=(l>>5)*8+j. B-frag: col=l&31, k=(l>>5)*8+j.
// C/D: col=lane&31, row=(reg&3)+8*(reg>>2)+4*(lane>>5)  [m74/m101].
// ---------------------------------------------------------------------------
#define NT 64  // K-tiles per slice: 4096/64

__global__ void __launch_bounds__(512, 2)
gemm8(const u16* __restrict__ A, const u16* __restrict__ Bm,
      float* __restrict__ part) {
  __shared__ u16 sA[2][2][128 * 64];  // [dbuf][half] 64 KiB
  __shared__ u16 sB[2][2][128 * 64];  // 64 KiB

  const int t = threadIdx.x;
  const int bm = blockIdx.x;  // 0..15
  const int bn = blockIdx.y;  // 0..3
  const int kz = blockIdx.z;  // 0..3
  const int wid = t >> 6, l = t & 63;
  const int wr = wid >> 2, wc = wid & 3;  // waves 2M x 4N
  const int l31 = l & 31, lhi = l >> 5;

  const u16* aT = A + (size_t)(bm * 256) * KD + kz * 4096;
  const u16* bT = Bm + (size_t)(bn * 256) * KD + kz * 4096;

  // A rows within 128-row half: wr*64 + mi*32 + l31 ; B rows: wc*32 + l31
  const int ar0 = wr * 64 + l31;        // mi=0
  const int ar1 = wr * 64 + 32 + l31;   // mi=1
  const int br = wc * 32 + l31;
  // 16B-chunk for k-step s: (s*2 + lhi) ^ (row & 7), in bf16 units *8
#define ACHUNK(row, s) (((row) * 64) + ((((s) * 2 + lhi) ^ ((row) & 7)) * 8))

  f32x16 acc[4][2];
#pragma unroll
  for (int i = 0; i < 4; ++i)
#pragma unroll
    for (int j = 0; j < 2; ++j)
      acc[i][j] = (f32x16)(0.f);

  bf16x8 aq[2][4];  // current A-quadrant: 2 m-frags x 4 k-steps
  bf16x8 b0[4];     // B half 0: 1 n-frag x 4 k-steps (live p0..p3)
  bf16x8 b1[4];     // B half 1 (live p1..p2)

  // Prologue (same as R3/R4): tile0 all halves + B0(1),A0(1) in flight.
  stage_half(aT, &sA[0][0][0], t);
  stage_half(aT + (size_t)128 * KD, &sA[0][1][0], t);
  stage_half(bT, &sB[0][0][0], t);
  stage_half(bT + (size_t)128 * KD, &sB[0][1][0], t);
  stage_half(bT + 64, &sB[1][0][0], t);
  stage_half(aT + 64, &sA[1][0][0], t);
  asm volatile("s_waitcnt vmcnt(4)" ::: "memory");
  __builtin_amdgcn_s_barrier();

  for (int T = 0; T < NT; ++T) {
    const int c = T & 1;

    // ---- p0: compute (qa0,qb0); read A0 + B0; stage A1(T+1) ----
#pragma unroll
    for (int s = 0; s < 4; ++s) {
      aq[0][s] = *(const bf16x8*)&sA[c][0][ACHUNK(ar0, s)];
      aq[1][s] = *(const bf16x8*)&sA[c][0][ACHUNK(ar1, s)];
      b0[s]    = *(const bf16x8*)&sB[c][0][ACHUNK(br, s)];
    }
    if (T + 1 < NT)
      stage_half(aT + (size_t)128 * KD + (T + 1) * 64, &sA[(T + 1) & 1][1][0], t);
    __builtin_amdgcn_s_barrier();
    asm volatile("s_waitcnt lgkmcnt(0)" ::: "memory");
    __builtin_amdgcn_sched_barrier(0);
    __builtin_amdgcn_s_setprio(1);
#pragma unroll
    for (int mi = 0; mi < 2; ++mi)
#pragma unroll
      for (int s = 0; s < 4; ++s)
        acc[mi][0] = __builtin_amdgcn_mfma_f32_32x32x16_bf16(
            aq[mi][s], b0[s], acc[mi][0], 0, 0, 0);
    __builtin_amdgcn_s_setprio(0);
    __builtin_amdgcn_s_barrier();

    // ---- p1: compute (qa0,qb1); read B1; stage B1(T+1) ----
#pragma unroll
    for (int s = 0; s < 4; ++s)
      b1[s] = *(const bf16x8*)&sB[c][1][ACHUNK(br, s)];
    if (T + 1 < NT)
      stage_half(bT + (size_t)128 * KD + (T + 1) * 64, &sB[(T + 1) & 1][1][0], t);
    __builtin_amdgcn_s_barrier();
    asm volatile("s_waitcnt lgkmcnt(0)" ::: "memory");
    __builtin_amdgcn_sched_barrier(0);
    __builtin_amdgcn_s_setprio(1);
#pragma unroll
    for (int mi = 0; mi < 2; ++mi)
#pragma unroll
      for (int s = 0; s < 4; ++s)
        acc[mi][1] = __builtin_amdgcn_mfma_f32_32x32x16_bf16(
            aq[mi][s], b1[s], acc[mi][1], 0, 0, 0);
    __builtin_amdgcn_s_setprio(0);
    __builtin_amdgcn_s_barrier();

    // ---- p2: compute (qa1,qb1); read A1; stage B0(T+2) ----
#pragma unroll
    for (int s = 0; s < 4; ++s) {
      aq[0][s] = *(const bf16x8*)&sA[c][1][ACHUNK(ar0, s)];
      aq[1][s] = *(const bf16x8*)&sA[c][1][ACHUNK(ar1, s)];
    }
    if (T + 2 < NT)
      stage_half(bT + (T + 2) * 64, &sB[T & 1][0][0], t);
    __builtin_amdgcn_s_barrier();
    asm volatile("s_waitcnt lgkmcnt(0)" ::: "memory");
    __builtin_amdgcn_sched_barrier(0);
    __builtin_amdgcn_s_setprio(1);
#pragma unroll
    for (int mi = 0; mi < 2; ++mi)
#pragma unroll
      for (int s = 0; s < 4; ++s)
        acc[2 + mi][1] = __builtin_amdgcn_mfma_f32_32x32x16_bf16(
            aq[mi][s], b1[s], acc[2 + mi][1], 0, 0, 0);
    __builtin_amdgcn_s_setprio(0);
    __builtin_amdgcn_s_barrier();

    // ---- p3: compute (qa1,qb0); no reads; stage A0(T+2); tile-end vmcnt ----
    if (T + 2 < NT)
      stage_half(aT + (T + 2) * 64, &sA[T & 1][0][0], t);
    __builtin_amdgcn_s_barrier();
    asm volatile("s_waitcnt lgkmcnt(0)" ::: "memory");
    __builtin_amdgcn_sched_barrier(0);
    __builtin_amdgcn_s_setprio(1);
#pragma unroll
    for (int mi = 0; mi < 2; ++mi)
#pragma unroll
      for (int s = 0; s < 4; ++s)
        acc[2 + mi][0] = __builtin_amdgcn_mfma_f32_32x32x16_bf16(
            aq[mi][s], b0[s], acc[2 + mi][0], 0, 0, 0);
    __builtin_amdgcn_s_setprio(0);
    if (T + 2 < NT) asm volatile("s_waitcnt vmcnt(4)" ::: "memory");
    else            asm volatile("s_waitcnt vmcnt(0)" ::: "memory");
    __builtin_amdgcn_s_barrier();
  }
#undef ACHUNK

  // partial C-write: frag (M=qa*2+mi, n=qb); within frag:
  // col = l&31, row = (reg&3) + 8*(reg>>2) + 4*(l>>5)
  float* pW = part + (size_t)kz * ((size_t)B_DIM * O_DIM);
#pragma unroll
  for (int M = 0; M < 4; ++M) {
    const int qa = M >> 1, mi = M & 1;
#pragma unroll
    for (int qb = 0; qb < 2; ++qb) {
      const int col = bn * 256 + qb * 128 + wc * 32 + l31;
      const int rbase = bm * 256 + qa * 128 + wr * 64 + mi * 32 + 4 * lhi;
#pragma unroll
      for (int reg = 0; reg < 16; ++reg) {
        const int row = rbase + (reg & 3) + 8 * (reg >> 2);
        pW[(size_t)row * O_DIM + col] = acc[M][qb][reg];
      }
    }
  }
}

// ---------------------------------------------------------------------------
// Reduce: out = p0+p1+p2+p3 + bias, vectorized f32x4.
// ---------------------------------------------------------------------------
__global__ void __launch_bounds__(256) reduce4(const float4* __restrict__ p,
                                               const float4* __restrict__ bias4,
                                               float4* __restrict__ out) {
  const int i = blockIdx.x * 256 + threadIdx.x;
  const size_t s = (size_t)B_DIM * O_DIM / 4;
  const float4 a = p[i], b = p[i + s], c = p[i + 2 * s], d = p[i + 3 * s];
  const float4 bb = bias4[i & 255];
  float4 r;
  r.x = a.x + b.x + c.x + d.x + bb.x;
  r.y = a.y + b.y + c.y + d.y + bb.y;
  r.z = a.z + b.z + c.z + d.z + bb.z;
  r.w = a.w + b.w + c.w + d.w + bb.w;
  out[i] = r;
}

// ---------------------------------------------------------------------------
// Fallback (R2): 128x64 2-phase kernel, no split-K. Used if ws too small.
// ---------------------------------------------------------------------------
#define BM 128
#define BN 64
#define BK 64

__global__ void __launch_bounds__(256, 2) gemm_bt(const u16* __restrict__ A,
                                                  const u16* __restrict__ Bm,
                                                  const float* __restrict__ bias,
                                                  float* __restrict__ C) {
  __shared__ u16 sA[BM * BK];
  __shared__ u16 sB[BN * BK];

  const int t = threadIdx.x;
  const int bm = blockIdx.x, bn = blockIdx.y;
  const int wid = t >> 6, l = t & 63;
  const int wr = wid >> 1, wc = wid & 1;
  const int lm = l & 15, lk = l >> 4;

  const u16* aG = A + (size_t)bm * BM * KD;
  const u16* bG = Bm + (size_t)bn * BN * KD;

  f32x4 acc[4][2];
#pragma unroll
  for (int mi = 0; mi < 4; ++mi)
#pragma unroll
    for (int ni = 0; ni < 2; ++ni)
      acc[mi][ni] = (f32x4){0.f, 0.f, 0.f, 0.f};

  for (int kt = 0; kt < KD; kt += BK) {
#pragma unroll
    for (int j = 0; j < 4; ++j) {
      const int chunk = j * 256 + t;
      const int row = chunk >> 3, slot = chunk & 7;
      const int c = slot ^ (row & 7);
      __builtin_amdgcn_global_load_lds((gu16*)(aG + (size_t)row * KD + kt + c * 8),
                                       (lu16*)(sA + chunk * 8), 16, 0, 0);
    }
#pragma unroll
    for (int j = 0; j < 2; ++j) {
      const int chunk = j * 256 + t;
      const int row = chunk >> 3, slot = chunk & 7;
      const int c = slot ^ (row & 7);
      __builtin_amdgcn_global_load_lds((gu16*)(bG + (size_t)row * KD + kt + c * 8),
                                       (lu16*)(sB + chunk * 8), 16, 0, 0);
    }
    __syncthreads();
#pragma unroll
    for (int kk = 0; kk < 2; ++kk) {
      const int s = (kk * 4 + lk) ^ (lm & 7);
      bf16x8 af[4], bfr[2];
#pragma unroll
      for (int mi = 0; mi < 4; ++mi)
        af[mi] = *(const bf16x8*)(sA + (wr * 64 + mi * 16 + lm) * BK + s * 8);
#pragma unroll
      for (int ni = 0; ni < 2; ++ni)
        bfr[ni] = *(const bf16x8*)(sB + (wc * 32 + ni * 16 + lm) * BK + s * 8);
#pragma unroll
      for (int mi = 0; mi < 4; ++mi)
#pragma unroll
        for (int ni = 0; ni < 2; ++ni)
          acc[mi][ni] = __builtin_amdgcn_mfma_f32_16x16x32_bf16(af[mi], bfr[ni],
                                                                acc[mi][ni], 0, 0, 0);
    }
    __syncthreads();
  }

#pragma unroll
  for (int ni = 0; ni < 2; ++ni) {
    const int col = bn * BN + wc * 32 + ni * 16 + lm;
    const float bv = bias[col];
#pragma unroll
    for (int mi = 0; mi < 4; ++mi) {
      const int row0 = bm * BM + wr * 64 + mi * 16 + lk * 4;
#pragma unroll
      for (int j = 0; j < 4; ++j)
        C[(size_t)(row0 + j) * O_DIM + col] = acc[mi][ni][j] + bv;
    }
  }
}

// ---------------------------------------------------------------------------
extern "C" void kernel_launch(void* const* d_in, const int* in_sizes, int n_in,
                              void* d_out, int out_size, void* d_ws, size_t ws_size,
                              hipStream_t stream) {
  const float* x = (const float*)d_in[0];
  const float* w = (const float*)d_in[1];
  const float* bias = (const float*)d_in[2];
  const float* centers = (const float*)d_in[3];
  const float* widths = (const float*)d_in[4];
  float* out = (float*)d_out;

  // ws: feat bf16 [4096][16384] = 128 MiB | wb bf16 [1024][16384] = 32 MiB |
  //     partials f32 [4][4096][1024] = 64 MiB
  u16* feat = (u16*)d_ws;
  u16* wb = (u16*)((char*)d_ws + (size_t)B_DIM * KD * 2);
  float* part = (float*)((char*)d_ws + (size_t)B_DIM * KD * 2 + (size_t)O_DIM * KD * 2);

  rbf_feat<<<(B_DIM * I_DIM) / 256, 256, 0, stream>>>(x, feat, centers, widths);
  cvt_w<<<(O_DIM * KD) / (256 * 8), 256, 0, stream>>>((const float4*)w, (u16x8*)wb);

  const size_t need = (size_t)B_DIM * KD * 2 + (size_t)O_DIM * KD * 2 +
                      4ull * B_DIM * O_DIM * 4;
  if (ws_size >= need) {
    dim3 grid(B_DIM / 256, O_DIM / 256, 4);
    gemm8<<<grid, 512, 0, stream>>>(feat, wb, part);
    reduce4<<<(B_DIM * O_DIM / 4) / 256, 256, 0, stream>>>(
        (const float4*)part, (const float4*)bias, (float4*)out);
  } else {
    dim3 grid(B_DIM / BM, O_DIM / BN);
    gemm_bt<<<grid, 256, 0, stream>>>(feat, wb, bias, out);
  }
}

// Round 7
// 182.124 us; speedup vs baseline: 1.1064x; 1.1064x over previous
//
#include <hip/hip_runtime.h>
#include <hip/hip_bf16.h>

// KAN layer: out[b,o] = sum_{i,k} exp(-(x[b,i]-c[k])^2/(2 w[k]^2)) * W[o,i,k] + bias[o]
// == GEMM: A = feat[B][I*K] (bf16), Bmat = W[O][I*K] (bf16), C = A * Bmat^T.
// M=4096, N=1024, Kd=16384.
// R7 = R6 with the prologue bug fixed: R6 forgot to pre-stage tile 1's
// half-0 buffers (B0(1), A0(1)) -> tile 1 read garbage (absmax 21.5).
// Restored the R3/R4 6-stage prologue + vmcnt(4). Loop body unchanged:
// 16x16x32 MFMA, TWO barriers per K-tile, reads issued early so compiler's
// per-register lgkm waits overlap LDS reads with MFMA.

#define B_DIM 4096
#define I_DIM 1024
#define O_DIM 1024
#define NK 16
#define KD (I_DIM * NK)  // 16384

typedef unsigned short u16;
typedef __attribute__((ext_vector_type(8))) __bf16 bf16x8;
typedef __attribute__((ext_vector_type(4))) float f32x4;
typedef __attribute__((ext_vector_type(8))) unsigned short u16x8;

typedef const __attribute__((address_space(1))) unsigned short gu16;
typedef __attribute__((address_space(3))) unsigned short lu16;

static __device__ __forceinline__ u16 f2bf(float f) {
  unsigned u = __float_as_uint(f);
  u += 0x7FFFu + ((u >> 16) & 1u);
  return (u16)(u >> 16);
}

// ---------------------------------------------------------------------------
// Phase 1: RBF features, bf16. One thread per (b,i): 16 exps, two 16B stores.
// ---------------------------------------------------------------------------
__global__ void __launch_bounds__(256) rbf_feat(const float* __restrict__ x,
                                                u16* __restrict__ feat,
                                                const float* __restrict__ centers,
                                                const float* __restrict__ widths) {
  const int idx = blockIdx.x * 256 + threadIdx.x;
  const float xv = x[idx];
  u16x8 lo, hi;
#pragma unroll
  for (int k = 0; k < 16; ++k) {
    const float c = centers[k];
    const float w = widths[k];
    const float s = -0.5f * __builtin_amdgcn_rcpf(w * w);
    const float d = xv - c;
    const u16 h = f2bf(__expf(d * d * s));
    if (k < 8) lo[k] = h; else hi[k - 8] = h;
  }
  u16x8* dst = (u16x8*)(feat + (size_t)idx * 16);
  dst[0] = lo;
  dst[1] = hi;
}

// ---------------------------------------------------------------------------
// Phase 1b: weights f32 -> bf16, 8 elements/thread.
// ---------------------------------------------------------------------------
__global__ void __launch_bounds__(256) cvt_w(const float4* __restrict__ w,
                                             u16x8* __restrict__ wb) {
  const size_t i = (size_t)blockIdx.x * 256 + threadIdx.x;
  const float4 a = w[2 * i];
  const float4 b = w[2 * i + 1];
  u16x8 o;
  o[0] = f2bf(a.x); o[1] = f2bf(a.y); o[2] = f2bf(a.z); o[3] = f2bf(a.w);
  o[4] = f2bf(b.x); o[5] = f2bf(b.y); o[6] = f2bf(b.z); o[7] = f2bf(b.w);
  wb[i] = o;
}

// ---------------------------------------------------------------------------
// Stage one 128x64 bf16 half-tile (16 KiB = 1024 x 16B chunks, 512 thr x 2).
// Linear LDS dest + inverse-swizzled global source (rule #21).
// ---------------------------------------------------------------------------
static __device__ __forceinline__ void stage_half(const u16* __restrict__ g,
                                                  u16* __restrict__ lds, int t) {
#pragma unroll
  for (int j = 0; j < 2; ++j) {
    const int chunk = j * 512 + t;
    const int row = chunk >> 3, slot = chunk & 7;
    const int c = slot ^ (row & 7);
    __builtin_amdgcn_global_load_lds((gu16*)(g + (size_t)row * KD + c * 8),
                                     (lu16*)(lds + chunk * 8), 16, 0, 0);
  }
}

// ---------------------------------------------------------------------------
// Main GEMM: 256x256 tile, BK=64, 8 waves (2M x 4N), split-K=4 (blockIdx.z).
// 16x16x32 MFMA (verified conflict-free read pattern). TWO barriers/K-tile:
//   entry: read A0(8)+B0(4)+B1(4); stage A1(T+1),B1(T+1);
//          p0: A0xB0, p1: A0xB1
//   mid barrier (protects sA/sB[c][0] for the T+2 stages)
//          read A1(8); stage B0(T+2),A0(T+2);
//          p2: A1xB1, p3: A1xB0
//   vmcnt(4) (tail: vmcnt(0)); end barrier.
// Overwrite ledger: B0/A0(T+2) -> [c][0], read only at entry (complete
// before mid via lgkmcnt(0)); A1/B1(T+1) -> [c^1][1], read last in tile T-1
// before its end barrier. vmcnt(4) at end of tile T retires everything
// except the 4 step-6 loads -> tile T+1's buffers all resident.
// Prologue MUST stage 6 half-tiles: tile 0 (4) + tile 1's half-0 (2),
// because in-loop staging only covers half-0 of T+2 and half-1 of T+1.
// ---------------------------------------------------------------------------
#define NT 64  // K-tiles per slice: 4096/64

__global__ void __launch_bounds__(512, 2)
gemm8(const u16* __restrict__ A, const u16* __restrict__ Bm,
      float* __restrict__ part) {
  __shared__ u16 sA[2][2][128 * 64];  // [dbuf][row-half] 64 KiB
  __shared__ u16 sB[2][2][128 * 64];  // 64 KiB

  const int t = threadIdx.x;
  const int bm = blockIdx.x;  // 0..15
  const int bn = blockIdx.y;  // 0..3
  const int kz = blockIdx.z;  // 0..3
  const int wid = t >> 6, l = t & 63;
  const int wr = wid >> 2, wc = wid & 3;  // waves 2M x 4N
  const int lm = l & 15, lk = l >> 4;

  const u16* aT = A + (size_t)(bm * 256) * KD + kz * 4096;
  const u16* bT = Bm + (size_t)(bn * 256) * KD + kz * 4096;

  const int swz0 = ((0 * 4 + lk) ^ (lm & 7)) * 8;  // kk=0 swizzled slot
  const int swz1 = ((1 * 4 + lk) ^ (lm & 7)) * 8;  // kk=1
  const int arow = wr * 64 + lm;  // + mi*16
  const int brow = wc * 32 + lm;  // + ni*16

  f32x4 acc[8][4];
#pragma unroll
  for (int i = 0; i < 8; ++i)
#pragma unroll
    for (int j = 0; j < 4; ++j)
      acc[i][j] = (f32x4){0.f, 0.f, 0.f, 0.f};

  // Prologue (R3/R4, verified): tile 0 all 4 halves + tile 1's half-0 pair.
  stage_half(aT, &sA[0][0][0], t);
  stage_half(aT + (size_t)128 * KD, &sA[0][1][0], t);
  stage_half(bT, &sB[0][0][0], t);
  stage_half(bT + (size_t)128 * KD, &sB[0][1][0], t);
  stage_half(bT + 64, &sB[1][0][0], t);
  stage_half(aT + 64, &sA[1][0][0], t);
  asm volatile("s_waitcnt vmcnt(4)" ::: "memory");
  __builtin_amdgcn_s_barrier();

  for (int T = 0; T < NT; ++T) {
    const int c = T & 1;

    // ---- entry reads: A0 (8 b128), B0 (4), B1 (4) ----
    bf16x8 aq[4][2], b0[2][2], b1[2][2];
#pragma unroll
    for (int mi = 0; mi < 4; ++mi) {
      aq[mi][0] = *(const bf16x8*)&sA[c][0][(arow + mi * 16) * 64 + swz0];
      aq[mi][1] = *(const bf16x8*)&sA[c][0][(arow + mi * 16) * 64 + swz1];
    }
#pragma unroll
    for (int ni = 0; ni < 2; ++ni) {
      b0[ni][0] = *(const bf16x8*)&sB[c][0][(brow + ni * 16) * 64 + swz0];
      b0[ni][1] = *(const bf16x8*)&sB[c][0][(brow + ni * 16) * 64 + swz1];
      b1[ni][0] = *(const bf16x8*)&sB[c][1][(brow + ni * 16) * 64 + swz0];
      b1[ni][1] = *(const bf16x8*)&sB[c][1][(brow + ni * 16) * 64 + swz1];
    }
    if (T + 1 < NT) {
      stage_half(aT + (size_t)128 * KD + (T + 1) * 64, &sA[(T + 1) & 1][1][0], t);
      stage_half(bT + (size_t)128 * KD + (T + 1) * 64, &sB[(T + 1) & 1][1][0], t);
    }

    // ---- p0: A0 x B0 ; p1: A0 x B1 (compiler inserts minimal lgkm waits) --
    __builtin_amdgcn_s_setprio(1);
#pragma unroll
    for (int mi = 0; mi < 4; ++mi)
#pragma unroll
      for (int ni = 0; ni < 2; ++ni)
#pragma unroll
        for (int kk = 0; kk < 2; ++kk)
          acc[mi][ni] = __builtin_amdgcn_mfma_f32_16x16x32_bf16(
              aq[mi][kk], b0[ni][kk], acc[mi][ni], 0, 0, 0);
#pragma unroll
    for (int mi = 0; mi < 4; ++mi)
#pragma unroll
      for (int ni = 0; ni < 2; ++ni)
#pragma unroll
        for (int kk = 0; kk < 2; ++kk)
          acc[mi][2 + ni] = __builtin_amdgcn_mfma_f32_16x16x32_bf16(
              aq[mi][kk], b1[ni][kk], acc[mi][2 + ni], 0, 0, 0);
    __builtin_amdgcn_s_setprio(0);

    // ---- mid barrier: all waves' reads of [c][0] are consumed/complete ----
    asm volatile("s_waitcnt lgkmcnt(0)" ::: "memory");
    __builtin_amdgcn_sched_barrier(0);
    __builtin_amdgcn_s_barrier();

    // ---- read A1 (8 b128); stage T+2 half-0 tiles ----
    bf16x8 aq2[4][2];
#pragma unroll
    for (int mi = 0; mi < 4; ++mi) {
      aq2[mi][0] = *(const bf16x8*)&sA[c][1][(arow + mi * 16) * 64 + swz0];
      aq2[mi][1] = *(const bf16x8*)&sA[c][1][(arow + mi * 16) * 64 + swz1];
    }
    if (T + 2 < NT) {
      stage_half(bT + (T + 2) * 64, &sB[T & 1][0][0], t);
      stage_half(aT + (T + 2) * 64, &sA[T & 1][0][0], t);
    }

    // ---- p2: A1 x B1 ; p3: A1 x B0 ----
    __builtin_amdgcn_s_setprio(1);
#pragma unroll
    for (int mi = 0; mi < 4; ++mi)
#pragma unroll
      for (int ni = 0; ni < 2; ++ni)
#pragma unroll
        for (int kk = 0; kk < 2; ++kk)
          acc[4 + mi][2 + ni] = __builtin_amdgcn_mfma_f32_16x16x32_bf16(
              aq2[mi][kk], b1[ni][kk], acc[4 + mi][2 + ni], 0, 0, 0);
#pragma unroll
    for (int mi = 0; mi < 4; ++mi)
#pragma unroll
      for (int ni = 0; ni < 2; ++ni)
#pragma unroll
        for (int kk = 0; kk < 2; ++kk)
          acc[4 + mi][ni] = __builtin_amdgcn_mfma_f32_16x16x32_bf16(
              aq2[mi][kk], b0[ni][kk], acc[4 + mi][ni], 0, 0, 0);
    __builtin_amdgcn_s_setprio(0);

    if (T + 2 < NT) asm volatile("s_waitcnt vmcnt(4)" ::: "memory");
    else            asm volatile("s_waitcnt vmcnt(0)" ::: "memory");
    __builtin_amdgcn_s_barrier();
  }

  // partial C-write: row=(lane>>4)*4+j, col=lane&15 within each 16x16 frag
  float* pW = part + (size_t)kz * ((size_t)B_DIM * O_DIM);
#pragma unroll
  for (int qa = 0; qa < 2; ++qa)
#pragma unroll
    for (int mi = 0; mi < 4; ++mi)
#pragma unroll
      for (int qb = 0; qb < 2; ++qb)
#pragma unroll
        for (int ni = 0; ni < 2; ++ni) {
          const int row0 = bm * 256 + qa * 128 + wr * 64 + mi * 16 + lk * 4;
          const int col = bn * 256 + qb * 128 + wc * 32 + ni * 16 + lm;
#pragma unroll
          for (int j = 0; j < 4; ++j)
            pW[(size_t)(row0 + j) * O_DIM + col] = acc[qa * 4 + mi][qb * 2 + ni][j];
        }
}

// ---------------------------------------------------------------------------
// Reduce: out = p0+p1+p2+p3 + bias, vectorized f32x4.
// ---------------------------------------------------------------------------
__global__ void __launch_bounds__(256) reduce4(const float4* __restrict__ p,
                                               const float4* __restrict__ bias4,
                                               float4* __restrict__ out) {
  const int i = blockIdx.x * 256 + threadIdx.x;
  const size_t s = (size_t)B_DIM * O_DIM / 4;
  const float4 a = p[i], b = p[i + s], c = p[i + 2 * s], d = p[i + 3 * s];
  const float4 bb = bias4[i & 255];
  float4 r;
  r.x = a.x + b.x + c.x + d.x + bb.x;
  r.y = a.y + b.y + c.y + d.y + bb.y;
  r.z = a.z + b.z + c.z + d.z + bb.z;
  r.w = a.w + b.w + c.w + d.w + bb.w;
  out[i] = r;
}

// ---------------------------------------------------------------------------
// Fallback (R2): 128x64 2-phase kernel, no split-K. Used if ws too small.
// ---------------------------------------------------------------------------
#define BM 128
#define BN 64
#define BK 64

__global__ void __launch_bounds__(256, 2) gemm_bt(const u16* __restrict__ A,
                                                  const u16* __restrict__ Bm,
                                                  const float* __restrict__ bias,
                                                  float* __restrict__ C) {
  __shared__ u16 sA[BM * BK];
  __shared__ u16 sB[BN * BK];

  const int t = threadIdx.x;
  const int bm = blockIdx.x, bn = blockIdx.y;
  const int wid = t >> 6, l = t & 63;
  const int wr = wid >> 1, wc = wid & 1;
  const int lm = l & 15, lk = l >> 4;

  const u16* aG = A + (size_t)bm * BM * KD;
  const u16* bG = Bm + (size_t)bn * BN * KD;

  f32x4 acc[4][2];
#pragma unroll
  for (int mi = 0; mi < 4; ++mi)
#pragma unroll
    for (int ni = 0; ni < 2; ++ni)
      acc[mi][ni] = (f32x4){0.f, 0.f, 0.f, 0.f};

  for (int kt = 0; kt < KD; kt += BK) {
#pragma unroll
    for (int j = 0; j < 4; ++j) {
      const int chunk = j * 256 + t;
      const int row = chunk >> 3, slot = chunk & 7;
      const int c = slot ^ (row & 7);
      __builtin_amdgcn_global_load_lds((gu16*)(aG + (size_t)row * KD + kt + c * 8),
                                       (lu16*)(sA + chunk * 8), 16, 0, 0);
    }
#pragma unroll
    for (int j = 0; j < 2; ++j) {
      const int chunk = j * 256 + t;
      const int row = chunk >> 3, slot = chunk & 7;
      const int c = slot ^ (row & 7);
      __builtin_amdgcn_global_load_lds((gu16*)(bG + (size_t)row * KD + kt + c * 8),
                                       (lu16*)(sB + chunk * 8), 16, 0, 0);
    }
    __syncthreads();
#pragma unroll
    for (int kk = 0; kk < 2; ++kk) {
      const int s = (kk * 4 + lk) ^ (lm & 7);
      bf16x8 af[4], bfr[2];
#pragma unroll
      for (int mi = 0; mi < 4; ++mi)
        af[mi] = *(const bf16x8*)(sA + (wr * 64 + mi * 16 + lm) * BK + s * 8);
#pragma unroll
      for (int ni = 0; ni < 2; ++ni)
        bfr[ni] = *(const bf16x8*)(sB + (wc * 32 + ni * 16 + lm) * BK + s * 8);
#pragma unroll
      for (int mi = 0; mi < 4; ++mi)
#pragma unroll
        for (int ni = 0; ni < 2; ++ni)
          acc[mi][ni] = __builtin_amdgcn_mfma_f32_16x16x32_bf16(af[mi], bfr[ni],
                                                                acc[mi][ni], 0, 0, 0);
    }
    __syncthreads();
  }

#pragma unroll
  for (int ni = 0; ni < 2; ++ni) {
    const int col = bn * BN + wc * 32 + ni * 16 + lm;
    const float bv = bias[col];
#pragma unroll
    for (int mi = 0; mi < 4; ++mi) {
      const int row0 = bm * BM + wr * 64 + mi * 16 + lk * 4;
#pragma unroll
      for (int j = 0; j < 4; ++j)
        C[(size_t)(row0 + j) * O_DIM + col] = acc[mi][ni][j] + bv;
    }
  }
}

// ---------------------------------------------------------------------------
extern "C" void kernel_launch(void* const* d_in, const int* in_sizes, int n_in,
                              void* d_out, int out_size, void* d_ws, size_t ws_size,
                              hipStream_t stream) {
  const float* x = (const float*)d_in[0];
  const float* w = (const float*)d_in[1];
  const float* bias = (const float*)d_in[2];
  const float* centers = (const float*)d_in[3];
  const float* widths = (const float*)d_in[4];
  float* out = (float*)d_out;

  // ws: feat bf16 [4096][16384] = 128 MiB | wb bf16 [1024][16384] = 32 MiB |
  //     partials f32 [4][4096][1024] = 64 MiB
  u16* feat = (u16*)d_ws;
  u16* wb = (u16*)((char*)d_ws + (size_t)B_DIM * KD * 2);
  float* part = (float*)((char*)d_ws + (size_t)B_DIM * KD * 2 + (size_t)O_DIM * KD * 2);

  rbf_feat<<<(B_DIM * I_DIM) / 256, 256, 0, stream>>>(x, feat, centers, widths);
  cvt_w<<<(O_DIM * KD) / (256 * 8), 256, 0, stream>>>((const float4*)w, (u16x8*)wb);

  const size_t need = (size_t)B_DIM * KD * 2 + (size_t)O_DIM * KD * 2 +
                      4ull * B_DIM * O_DIM * 4;
  if (ws_size >= need) {
    dim3 grid(B_DIM / 256, O_DIM / 256, 4);
    gemm8<<<grid, 512, 0, stream>>>(feat, wb, part);
    reduce4<<<(B_DIM * O_DIM / 4) / 256, 256, 0, stream>>>(
        (const float4*)part, (const float4*)bias, (float4*)out);
  } else {
    dim3 grid(B_DIM / BM, O_DIM / BN);
    gemm_bt<<<grid, 256, 0, stream>>>(feat, wb, bias, out);
  }
}